// Round 11
// baseline (4884.216 us; speedup 1.0000x reference)
//
#include <hip/hip_runtime.h>
#include <hip/hip_bf16.h>
#include <math.h>

#define B    64
#define T    256
#define H    1024
#define G4   4096
#define TC   64           // timesteps per x_proj chunk
#define NCH  (T / TC)
#define NBLK 256          // persistent blocks (4 h-cols each)
#define FSTR 16           // flag stride in ints (64B apart)

typedef __attribute__((ext_vector_type(8))) short bf16x8;
typedef __attribute__((ext_vector_type(4))) short bf16x4;
typedef __attribute__((ext_vector_type(4))) float f32x4;

__device__ __forceinline__ unsigned short f2bf(float x) {
    union { float f; unsigned u; } v; v.f = x;
    unsigned r = v.u + 0x7fffu + ((v.u >> 16) & 1u);   // RNE
    return (unsigned short)(r >> 16);
}
__device__ __forceinline__ float bf2f(unsigned short s) {
    union { unsigned u; float f; } v; v.u = ((unsigned)s) << 16;
    return v.f;
}
__device__ __forceinline__ float sigm_f(float x) {
    return 1.f / (1.f + __expf(-x));
}
__device__ __forceinline__ float tanh_f(float x) {
    float e = __expf(2.f * x);
    return (e - 1.f) / (e + 1.f);
}

// ---------------------------------------------------------------------------
__global__ __launch_bounds__(256) void cast_f32_bf16(
    const float* __restrict__ src, unsigned short* __restrict__ dst, int n8)
{
    int i = blockIdx.x * 256 + threadIdx.x;
    if (i >= n8) return;
    const float4* s = (const float4*)(src + (size_t)i * 8);
    float4 a = s[0], b = s[1];
    bf16x8 o;
    o[0] = f2bf(a.x); o[1] = f2bf(a.y); o[2] = f2bf(a.z); o[3] = f2bf(a.w);
    o[4] = f2bf(b.x); o[5] = f2bf(b.y); o[6] = f2bf(b.z); o[7] = f2bf(b.w);
    *(bf16x8*)(dst + (size_t)i * 8) = o;
}

// ---------------------------------------------------------------------------
__global__ __launch_bounds__(256) void gather_x(
    const int* __restrict__ tgt, const float* __restrict__ emb,
    unsigned short* __restrict__ xch, int t0)
{
    int tid = threadIdx.x;
    int r   = blockIdx.x * 2 + (tid >> 7);     // 0..4095
    int c   = (tid & 127) * 8;
    int b   = r & 63, tcc = r >> 6;
    int token = tgt[b * T + t0 + tcc];
    const float4* s = (const float4*)(emb + (size_t)token * H + c);
    float4 x0 = s[0], x1 = s[1];
    bf16x8 o;
    o[0] = f2bf(x0.x); o[1] = f2bf(x0.y); o[2] = f2bf(x0.z); o[3] = f2bf(x0.w);
    o[4] = f2bf(x1.x); o[5] = f2bf(x1.y); o[6] = f2bf(x1.z); o[7] = f2bf(x1.w);
    *(bf16x8*)(xch + (size_t)r * H + c) = o;
}

// ---------------------------------------------------------------------------
// x_proj chunk GEMM (unchanged — proven since round 2)
// ---------------------------------------------------------------------------
__global__ __launch_bounds__(256) void gemm_xproj(
    const unsigned short* __restrict__ A,   // x chunk bf16 [4096][1024]
    const unsigned short* __restrict__ Bt,  // W_ih bf16 [4096][1024]
    unsigned short* __restrict__ C)         // [4096][4096]
{
    __shared__ unsigned short As[128 * 64], Bs[128 * 64];
    const int tid  = threadIdx.x;
    const int brow = (blockIdx.x >> 5) * 128;
    const int bcol = (blockIdx.x & 31) * 128;
    const int w = tid >> 6, lane = tid & 63;
    const int wr = w >> 1, wc = w & 1;
    const int lr = lane & 15, lg = lane >> 4;

    f32x4 acc[4][4] = {};

    for (int kc = 0; kc < H; kc += 64) {
        if (kc) __syncthreads();
        #pragma unroll
        for (int i = 0; i < 4; ++i) {
            int sf  = i * 256 + tid;
            int row = sf >> 3, s = sf & 7;
            int col = kc + s * 8;
            *(bf16x8*)(As + row * 64 + ((s ^ (row & 7)) * 8)) =
                *(const bf16x8*)(A + (size_t)(brow + row) * H + col);
            *(bf16x8*)(Bs + row * 64 + ((s ^ (row & 7)) * 8)) =
                *(const bf16x8*)(Bt + (size_t)(bcol + row) * H + col);
        }
        __syncthreads();
        #pragma unroll
        for (int kk = 0; kk < 2; ++kk) {
            bf16x8 af[4], bv[4];
            #pragma unroll
            for (int m = 0; m < 4; ++m) {
                int row = wr * 64 + m * 16 + lr;
                int s   = kk * 4 + lg;
                af[m] = *(const bf16x8*)(As + row * 64 + ((s ^ (row & 7)) * 8));
            }
            #pragma unroll
            for (int n = 0; n < 4; ++n) {
                int row = wc * 64 + n * 16 + lr;
                int s   = kk * 4 + lg;
                bv[n] = *(const bf16x8*)(Bs + row * 64 + ((s ^ (row & 7)) * 8));
            }
            #pragma unroll
            for (int m = 0; m < 4; ++m)
                #pragma unroll
                for (int n = 0; n < 4; ++n)
                    acc[m][n] = __builtin_amdgcn_mfma_f32_16x16x32_bf16(
                        af[m], bv[n], acc[m][n], 0, 0, 0);
        }
    }
    #pragma unroll
    for (int m = 0; m < 4; ++m)
        #pragma unroll
        for (int n = 0; n < 4; ++n)
            #pragma unroll
            for (int r = 0; r < 4; ++r) {
                int row = brow + wr * 64 + m * 16 + lg * 4 + r;
                int col = bcol + wc * 64 + n * 16 + lr;
                C[(size_t)row * G4 + col] = f2bf(acc[m][n][r]);
            }
}

// ---------------------------------------------------------------------------
// persistent chunk recurrence — 256 blocks x 256 thr (1/CU), 4 h-cols/block.
// Key changes vs r10:
//  * whole machine used; wave = m-tile (4 waves), ONE 16-wide n-tile/block ->
//    h read exactly once per block (no intra-block duplication);
//  * K-slice-gated pipeline: slice ks*4+lg consumes producer 2*(ks*4+lg)(+1);
//    fast path = single bulk flag check; slow path polls per 1/4-of-K group
//    (64 producers), so MFMA on ready slices overlaps laggards' publishes;
//  * producer-major hchain [slot][256][64][4]: publish = 64 lanes x 8B
//    contiguous (8 full 64B lines); A-frag = two 8B loads, shufflevector.
// ---------------------------------------------------------------------------
__global__ __launch_bounds__(256) void lstm_chunk(
    const unsigned short* __restrict__ xproj,  // [TC][B][4096] bf16
    const unsigned short* __restrict__ whh,    // [4096][1024] bf16
    const float* __restrict__ bih, const float* __restrict__ bhh,
    unsigned short* __restrict__ hchain,       // [TC+1][NBLK][64][4] bf16
    float* __restrict__ cbuf,                  // [B][H] f32
    float* __restrict__ outputs,               // [B][T][H] f32
    int* __restrict__ flags,                   // [NBLK*FSTR]
    int t0)
{
    __shared__ bf16x8 Ws[16 * 128];            // 32 KB, swizzled 16B slots
    __shared__ float  gst[64][20];             // [batch][v=q*4+jc]
    __shared__ unsigned short hsh[64][4];      // new h slice

    const int tid = threadIdx.x;
    const int jb  = blockIdx.x;
    const int j0  = jb * 4;

    // stage W_hh slice: rows v = q*4+jc -> global row q*H + j0 + jc
    #pragma unroll
    for (int it = 0; it < 8; ++it) {
        int f = it * 256 + tid;                // 16B-slot id, 0..2047
        int v = f >> 7, s = f & 127;
        int grow = (v >> 2) * H + j0 + (v & 3);
        Ws[v * 128 + (s ^ (v & 7))] =
            *(const bf16x8*)(whh + (size_t)grow * H + s * 8);
    }

    const int w = tid >> 6, lane = tid & 63;
    const int m = w;                           // wave = m-tile 0..3
    const int lr = lane & 15, lg = lane >> 4;
    const int vrow = lr, vx = lr & 7;

    // epilogue mapping: 256 threads, 1 thread = 1 (b, jc) cell
    const int b_e  = tid >> 2;                 // 0..63
    const int jc_e = tid & 3;
    const int hj   = j0 + jc_e;
    float breg[4];
    #pragma unroll
    for (int qq = 0; qq < 4; ++qq)
        breg[qq] = bih[qq * H + hj] + bhh[qq * H + hj];
    float creg = cbuf[b_e * H + hj];
    __syncthreads();

    for (int tc8 = 0; tc8 < TC; tc8 += 8) {
        float oreg[8];
        #pragma unroll
        for (int p = 0; p < 8; ++p) {
            const int tcs    = tc8 + p;
            const int target = t0 + tcs;

            // prefetch x_proj gate values (independent of h)
            float xpv[4];
            #pragma unroll
            for (int qq = 0; qq < 4; ++qq)
                xpv[qq] = bf2f(xproj[((size_t)tcs * B + b_e) * G4
                                     + qq * H + hj]);

            const unsigned short* hc     = hchain + (size_t)tcs * B * H;
            unsigned short*       hn_buf = hchain + (size_t)(tcs + 1) * B * H;

            // bulk flag check (single try; 4 flags per lane -> all 256)
            int f0 = __hip_atomic_load(&flags[(lane * 4 + 0) * FSTR],
                        __ATOMIC_RELAXED, __HIP_MEMORY_SCOPE_AGENT);
            int f1 = __hip_atomic_load(&flags[(lane * 4 + 1) * FSTR],
                        __ATOMIC_RELAXED, __HIP_MEMORY_SCOPE_AGENT);
            int f2 = __hip_atomic_load(&flags[(lane * 4 + 2) * FSTR],
                        __ATOMIC_RELAXED, __HIP_MEMORY_SCOPE_AGENT);
            int f3 = __hip_atomic_load(&flags[(lane * 4 + 3) * FSTR],
                        __ATOMIC_RELAXED, __HIP_MEMORY_SCOPE_AGENT);
            int rdy = __all(f0 >= target && f1 >= target &&
                            f2 >= target && f3 >= target);

            // K loop, gated per 1/4-of-K group when not all ready
            f32x4 acc = {};
            #pragma unroll
            for (int g = 0; g < 4; ++g) {
                if (!rdy) {
                    while (true) {
                        int fv = __hip_atomic_load(
                            &flags[(g * 64 + lane) * FSTR],
                            __ATOMIC_RELAXED, __HIP_MEMORY_SCOPE_AGENT);
                        if (__all(fv >= target)) break;
                        __builtin_amdgcn_s_sleep(1);
                    }
                }
                #pragma unroll
                for (int k8 = 0; k8 < 8; ++k8) {
                    int sl = (g * 8 + k8) * 4 + lg;      // K-slice 0..127
                    bf16x8 bw = Ws[vrow * 128 + (sl ^ vx)];
                    const unsigned short* pa =
                        hc + ((size_t)(sl * 2) * 64 + m * 16 + lr) * 4;
                    bf16x4 lo = *(const bf16x4*)pa;
                    bf16x4 hi = *(const bf16x4*)(pa + 256);
                    bf16x8 av = __builtin_shufflevector(lo, hi,
                                    0, 1, 2, 3, 4, 5, 6, 7);
                    acc = __builtin_amdgcn_mfma_f32_16x16x32_bf16(
                        av, bw, acc, 0, 0, 0);
                }
            }
            #pragma unroll
            for (int r = 0; r < 4; ++r)
                gst[m * 16 + lg * 4 + r][vrow] = acc[r];
            __syncthreads();

            // cell epilogue: 1 thread = 1 (b, jc) cell
            {
                float g[4];
                #pragma unroll
                for (int qq = 0; qq < 4; ++qq)
                    g[qq] = gst[b_e][qq * 4 + jc_e] + breg[qq] + xpv[qq];
                float ig = sigm_f(g[0]);
                float fg = sigm_f(g[1]);
                float gg = tanh_f(g[2]);
                float og = sigm_f(g[3]);
                float cn = fg * creg + ig * gg;
                float hnv = og * tanh_f(cn);
                creg = cn;
                oreg[p] = hnv;
                hsh[b_e][jc_e] = f2bf(hnv);
            }
            __syncthreads();

            // wave 0: publish block's 512B slice (8 full lines), then
            // RELEASE flag (wave-level vmcnt drain orders the publish)
            if (tid < 64) {
                union { unsigned short s[4]; unsigned long long u; } pk;
                #pragma unroll
                for (int i = 0; i < 4; ++i)
                    pk.s[i] = hsh[tid][i];
                __hip_atomic_store(
                    (unsigned long long*)(hn_buf + ((size_t)jb * 64 + tid) * 4),
                    pk.u, __ATOMIC_RELAXED, __HIP_MEMORY_SCOPE_AGENT);
            }
            if (tid == 0)
                __hip_atomic_store(&flags[jb * FSTR], target + 1,
                                   __ATOMIC_RELEASE, __HIP_MEMORY_SCOPE_AGENT);
        }
        // flush outputs (HBM) once per 8 steps — off the handoff path
        #pragma unroll
        for (int p = 0; p < 8; ++p) {
            int t = t0 + tc8 + p;
            outputs[((size_t)b_e * T + t) * H + hj] = oreg[p];
        }
    }

    cbuf[b_e * H + hj] = creg;
}

// ---------------------------------------------------------------------------
// init h slot 0 in producer-major layout: slot0[j>>2][b][j&3] = h0[b][j]
__global__ __launch_bounds__(256) void init_state(
    const float* __restrict__ h0, const float* __restrict__ c0,
    unsigned short* __restrict__ hb, float* __restrict__ cb)
{
    int i = blockIdx.x * 256 + threadIdx.x;    // 0..65535
    int b = i >> 10, j = i & 1023;
    hb[(size_t)(j >> 2) * 256 + b * 4 + (j & 3)] = f2bf(h0[i]);
    cb[i] = c0[i];
}

__global__ __launch_bounds__(256) void reset_flags(int* __restrict__ flags)
{
    __hip_atomic_store(&flags[threadIdx.x * FSTR], 0,
                       __ATOMIC_RELAXED, __HIP_MEMORY_SCOPE_AGENT);
}

// copy slot TC -> slot 0 (layout-identical dword copy)
__global__ __launch_bounds__(256) void copy_h(
    const unsigned short* __restrict__ src, unsigned short* __restrict__ dst)
{
    int i = blockIdx.x * 256 + threadIdx.x;    // dword index
    ((unsigned*)dst)[i] = ((const unsigned*)src)[i];
}

__global__ __launch_bounds__(256) void finalize(
    const float* __restrict__ outputs, const float* __restrict__ cfin,
    float* __restrict__ outh, float* __restrict__ outc)
{
    int i = blockIdx.x * 256 + threadIdx.x;    // 0..65535
    int b = i >> 10, j = i & 1023;
    outh[i] = outputs[((size_t)b * T + (T - 1)) * H + j];
    outc[i] = cfin[i];
}

// ---------------------------------------------------------------------------
extern "C" void kernel_launch(void* const* d_in, const int* in_sizes, int n_in,
                              void* d_out, int out_size, void* d_ws, size_t ws_size,
                              hipStream_t stream)
{
    const int*   tgt = (const int*)  d_in[0];
    const float* h0  = (const float*)d_in[1];
    const float* c0  = (const float*)d_in[2];
    const float* emb = (const float*)d_in[5];
    const float* Wih = (const float*)d_in[6];
    const float* Whh = (const float*)d_in[7];
    const float* bih = (const float*)d_in[8];
    const float* bhh = (const float*)d_in[9];

    float* out     = (float*)d_out;
    float* outputs = out;                                  // [B][T][H]
    float* out_h   = out + (size_t)B * T * H;
    float* out_c   = out_h + B * H;

    // ws layout — ~56.5 MB
    unsigned short* xproj  = (unsigned short*)d_ws;            // TC*B*G4
    unsigned short* xch    = xproj  + (size_t)TC * B * G4;     // TC*B*H
    unsigned short* wih    = xch    + (size_t)TC * B * H;      // G4*H
    unsigned short* whh    = wih    + (size_t)G4 * H;          // G4*H
    unsigned short* hchain = whh    + (size_t)G4 * H;          // (TC+1)*B*H
    float*          cbuf   = (float*)(hchain + (size_t)(TC + 1) * B * H);
    int*            flags  = (int*)(cbuf + (size_t)B * H);     // NBLK*FSTR

    cast_f32_bf16<<<2048, 256, 0, stream>>>(Wih, wih, (G4 * H) / 8);
    cast_f32_bf16<<<2048, 256, 0, stream>>>(Whh, whh, (G4 * H) / 8);
    init_state<<<(B * H) / 256, 256, 0, stream>>>(h0, c0, hchain, cbuf);
    reset_flags<<<1, NBLK, 0, stream>>>(flags);

    for (int ci = 0; ci < NCH; ++ci) {
        gather_x<<<(TC * B) / 2, 256, 0, stream>>>(tgt, emb, xch, ci * TC);
        gemm_xproj<<<(TC * B / 128) * (G4 / 128), 256, 0, stream>>>(xch, wih, xproj);
        if (ci) copy_h<<<(B * H / 2) / 256, 256, 0, stream>>>(
                    hchain + (size_t)TC * B * H, hchain);
        int t0 = ci * TC;
        void* args[] = { (void*)&xproj, (void*)&whh, (void*)&bih, (void*)&bhh,
                         (void*)&hchain, (void*)&cbuf, (void*)&outputs,
                         (void*)&flags, (void*)&t0 };
        hipLaunchCooperativeKernel((void*)lstm_chunk, dim3(NBLK), dim3(256),
                                   args, 0, stream);
    }
    finalize<<<(B * H) / 256, 256, 0, stream>>>(outputs, cbuf, out_h, out_c);
}

// Round 12
// 2459.944 us; speedup vs baseline: 1.9855x; 1.9855x over previous
//
#include <hip/hip_runtime.h>
#include <hip/hip_bf16.h>
#include <math.h>

#define B    64
#define T    256
#define H    1024
#define G4   4096
#define TC   64           // timesteps per x_proj chunk
#define NCH  (T / TC)
#define NBLK 128          // persistent blocks (8 h-cols each)
#define FSTR 16           // flag stride in ints (64B apart)

typedef __attribute__((ext_vector_type(8))) short bf16x8;
typedef __attribute__((ext_vector_type(4))) float f32x4;

__device__ __forceinline__ unsigned short f2bf(float x) {
    union { float f; unsigned u; } v; v.f = x;
    unsigned r = v.u + 0x7fffu + ((v.u >> 16) & 1u);   // RNE
    return (unsigned short)(r >> 16);
}
__device__ __forceinline__ float bf2f(unsigned short s) {
    union { unsigned u; float f; } v; v.u = ((unsigned)s) << 16;
    return v.f;
}
__device__ __forceinline__ float sigm_f(float x) {
    return 1.f / (1.f + __expf(-x));
}
__device__ __forceinline__ float tanh_f(float x) {
    float e = __expf(2.f * x);
    return (e - 1.f) / (e + 1.f);
}

// ---------------------------------------------------------------------------
__global__ __launch_bounds__(256) void cast_f32_bf16(
    const float* __restrict__ src, unsigned short* __restrict__ dst, int n8)
{
    int i = blockIdx.x * 256 + threadIdx.x;
    if (i >= n8) return;
    const float4* s = (const float4*)(src + (size_t)i * 8);
    float4 a = s[0], b = s[1];
    bf16x8 o;
    o[0] = f2bf(a.x); o[1] = f2bf(a.y); o[2] = f2bf(a.z); o[3] = f2bf(a.w);
    o[4] = f2bf(b.x); o[5] = f2bf(b.y); o[6] = f2bf(b.z); o[7] = f2bf(b.w);
    *(bf16x8*)(dst + (size_t)i * 8) = o;
}

// ---------------------------------------------------------------------------
__global__ __launch_bounds__(256) void gather_x(
    const int* __restrict__ tgt, const float* __restrict__ emb,
    unsigned short* __restrict__ xch, int t0)
{
    int tid = threadIdx.x;
    int r   = blockIdx.x * 2 + (tid >> 7);     // 0..4095
    int c   = (tid & 127) * 8;
    int b   = r & 63, tcc = r >> 6;
    int token = tgt[b * T + t0 + tcc];
    const float4* s = (const float4*)(emb + (size_t)token * H + c);
    float4 x0 = s[0], x1 = s[1];
    bf16x8 o;
    o[0] = f2bf(x0.x); o[1] = f2bf(x0.y); o[2] = f2bf(x0.z); o[3] = f2bf(x0.w);
    o[4] = f2bf(x1.x); o[5] = f2bf(x1.y); o[6] = f2bf(x1.z); o[7] = f2bf(x1.w);
    *(bf16x8*)(xch + (size_t)r * H + c) = o;
}

// ---------------------------------------------------------------------------
// x_proj chunk GEMM (unchanged — proven since round 2)
// ---------------------------------------------------------------------------
__global__ __launch_bounds__(256) void gemm_xproj(
    const unsigned short* __restrict__ A,   // x chunk bf16 [4096][1024]
    const unsigned short* __restrict__ Bt,  // W_ih bf16 [4096][1024]
    unsigned short* __restrict__ C)         // [4096][4096]
{
    __shared__ unsigned short As[128 * 64], Bs[128 * 64];
    const int tid  = threadIdx.x;
    const int brow = (blockIdx.x >> 5) * 128;
    const int bcol = (blockIdx.x & 31) * 128;
    const int w = tid >> 6, lane = tid & 63;
    const int wr = w >> 1, wc = w & 1;
    const int lr = lane & 15, lg = lane >> 4;

    f32x4 acc[4][4] = {};

    for (int kc = 0; kc < H; kc += 64) {
        if (kc) __syncthreads();
        #pragma unroll
        for (int i = 0; i < 4; ++i) {
            int sf  = i * 256 + tid;
            int row = sf >> 3, s = sf & 7;
            int col = kc + s * 8;
            *(bf16x8*)(As + row * 64 + ((s ^ (row & 7)) * 8)) =
                *(const bf16x8*)(A + (size_t)(brow + row) * H + col);
            *(bf16x8*)(Bs + row * 64 + ((s ^ (row & 7)) * 8)) =
                *(const bf16x8*)(Bt + (size_t)(bcol + row) * H + col);
        }
        __syncthreads();
        #pragma unroll
        for (int kk = 0; kk < 2; ++kk) {
            bf16x8 af[4], bv[4];
            #pragma unroll
            for (int m = 0; m < 4; ++m) {
                int row = wr * 64 + m * 16 + lr;
                int s   = kk * 4 + lg;
                af[m] = *(const bf16x8*)(As + row * 64 + ((s ^ (row & 7)) * 8));
            }
            #pragma unroll
            for (int n = 0; n < 4; ++n) {
                int row = wc * 64 + n * 16 + lr;
                int s   = kk * 4 + lg;
                bv[n] = *(const bf16x8*)(Bs + row * 64 + ((s ^ (row & 7)) * 8));
            }
            #pragma unroll
            for (int m = 0; m < 4; ++m)
                #pragma unroll
                for (int n = 0; n < 4; ++n)
                    acc[m][n] = __builtin_amdgcn_mfma_f32_16x16x32_bf16(
                        af[m], bv[n], acc[m][n], 0, 0, 0);
        }
    }
    #pragma unroll
    for (int m = 0; m < 4; ++m)
        #pragma unroll
        for (int n = 0; n < 4; ++n)
            #pragma unroll
            for (int r = 0; r < 4; ++r) {
                int row = brow + wr * 64 + m * 16 + lg * 4 + r;
                int col = bcol + wc * 64 + n * 16 + lr;
                C[(size_t)row * G4 + col] = f2bf(acc[m][n][r]);
            }
}

// ---------------------------------------------------------------------------
// persistent chunk recurrence — r10 skeleton (128 blocks x 512 thr, producer-
// major hchain, full-line publish) with two changes:
//  * wave = (m-tile 0..3, K-half 0..1), A reused in-register across BOTH
//    n-tiles -> per-block h read halves to 128 KB (no duplicate A rows);
//    partials joined via gst[2] with a 2-way add in the epilogue;
//  * early-start: K-half kh depends only on producers [64kh, 64kh+64), so
//    each wave polls ITS half's 64 flags (lane l <-> flag kh*64+l) and goes
//    straight into MFMA with NO barrier — the ready half's MFMA overlaps the
//    lagging half's producer tail. 2 barriers/step (gst-join, hsh-join).
// ---------------------------------------------------------------------------
__global__ __launch_bounds__(512) void lstm_chunk(
    const unsigned short* __restrict__ xproj,  // [TC][B][4096] bf16
    const unsigned short* __restrict__ whh,    // [4096][1024] bf16
    const float* __restrict__ bih, const float* __restrict__ bhh,
    unsigned short* __restrict__ hchain,       // [TC+1][NBLK][64][8] bf16
    float* __restrict__ cbuf,                  // [B][H] f32
    float* __restrict__ outputs,               // [B][T][H] f32
    int* __restrict__ flags,                   // [NBLK*FSTR]
    int t0)
{
    __shared__ bf16x8 Ws[32 * 128];            // 64 KB, swizzled 16B slots
    __shared__ float  gst[2][64][36];          // [kh][batch][v=q*8+jc]
    __shared__ unsigned short hsh[8][72];      // [jc][batch] new h slice

    const int tid = threadIdx.x;
    const int jb  = blockIdx.x;
    const int j0  = jb * 8;

    // stage W_hh slice: rows v = q*8+jc -> global row q*H + j0 + jc
    #pragma unroll
    for (int it = 0; it < 8; ++it) {
        int f = it * 512 + tid;                // 16B-slot id, 0..4095
        int v = f >> 7, s = f & 127;
        int grow = (v >> 3) * H + j0 + (v & 7);
        Ws[v * 128 + (s ^ (v & 7))] =
            *(const bf16x8*)(whh + (size_t)grow * H + s * 8);
    }

    const int w = tid >> 6, lane = tid & 63;
    const int m = w & 3, kh = w >> 2;          // wave = (m-tile, K-half)
    const int lr = lane & 15, lg = lane >> 4;
    const int vx = lr & 7;                     // swizzle key (same both n-tiles)

    // epilogue mapping: all 512 threads, 1 thread = 1 (b, jc) cell
    const int b_e  = tid >> 3;                 // 0..63
    const int jc_e = tid & 7;
    const int hj   = j0 + jc_e;
    float breg[4];
    #pragma unroll
    for (int qq = 0; qq < 4; ++qq)
        breg[qq] = bih[qq * H + hj] + bhh[qq * H + hj];
    float creg = cbuf[b_e * H + hj];
    __syncthreads();

    for (int tc8 = 0; tc8 < TC; tc8 += 8) {
        float oreg[8];
        #pragma unroll
        for (int p = 0; p < 8; ++p) {
            const int tcs    = tc8 + p;
            const int target = t0 + tcs;

            // prefetch x_proj gate values (independent of h)
            float xpv[4];
            #pragma unroll
            for (int qq = 0; qq < 4; ++qq)
                xpv[qq] = bf2f(xproj[((size_t)tcs * B + b_e) * G4
                                     + qq * H + hj]);

            const unsigned short* hc     = hchain + (size_t)tcs * B * H;
            unsigned short*       hn_buf = hchain + (size_t)(tcs + 1) * B * H;

            // per-wave poll of OWN K-half's 64 producers; no barrier after —
            // this wave's MFMA starts as soon as its half is published
            while (true) {
                int fv = __hip_atomic_load(&flags[(kh * 64 + lane) * FSTR],
                            __ATOMIC_RELAXED, __HIP_MEMORY_SCOPE_AGENT);
                if (__all(fv >= target)) break;
                __builtin_amdgcn_s_sleep(1);
            }

            // h @ W_hh^T over this wave's K-half; A reused for both n-tiles
            f32x4 acc0 = {}, acc1 = {};
            #pragma unroll
            for (int ks = 0; ks < 16; ++ks) {
                int s = kh * 64 + ks * 4 + lg;         // K-slice 0..127
                bf16x8 av = *(const bf16x8*)(hc
                    + ((size_t)s * 64 + m * 16 + lr) * 8);
                bf16x8 bw0 = Ws[lr * 128 + (s ^ vx)];
                bf16x8 bw1 = Ws[(16 + lr) * 128 + (s ^ vx)];
                acc0 = __builtin_amdgcn_mfma_f32_16x16x32_bf16(av, bw0, acc0,
                                                               0, 0, 0);
                acc1 = __builtin_amdgcn_mfma_f32_16x16x32_bf16(av, bw1, acc1,
                                                               0, 0, 0);
            }
            #pragma unroll
            for (int r = 0; r < 4; ++r) {
                gst[kh][m * 16 + lg * 4 + r][lr]      = acc0[r];
                gst[kh][m * 16 + lg * 4 + r][16 + lr] = acc1[r];
            }
            __syncthreads();   // barrier A: gst join (both halves)

            // cell epilogue: 1 thread = 1 (b, jc) cell; h slice -> hsh LDS
            {
                float g[4];
                #pragma unroll
                for (int qq = 0; qq < 4; ++qq)
                    g[qq] = gst[0][b_e][qq * 8 + jc_e]
                          + gst[1][b_e][qq * 8 + jc_e]
                          + breg[qq] + xpv[qq];
                float ig = sigm_f(g[0]);
                float fg = sigm_f(g[1]);
                float gg = tanh_f(g[2]);
                float og = sigm_f(g[3]);
                float cn = fg * creg + ig * gg;
                float hnv = og * tanh_f(cn);
                creg = cn;
                oreg[p] = hnv;
                hsh[jc_e][b_e] = f2bf(hnv);
            }
            __syncthreads();   // barrier B: hsh join

            // wave 0: publish block's contiguous 1KB slice (16 full lines),
            // then RELEASE flag (orders wave-0 publish stores)
            if (tid < 64) {
                union { bf16x8 v; unsigned long long u[2]; } pk;
                #pragma unroll
                for (int i = 0; i < 8; ++i)
                    pk.v[i] = (short)hsh[i][tid];
                unsigned long long* dst = (unsigned long long*)(hn_buf
                    + ((size_t)jb * 64 + tid) * 8);
                __hip_atomic_store(dst,     pk.u[0], __ATOMIC_RELAXED,
                                   __HIP_MEMORY_SCOPE_AGENT);
                __hip_atomic_store(dst + 1, pk.u[1], __ATOMIC_RELAXED,
                                   __HIP_MEMORY_SCOPE_AGENT);
            }
            if (tid == 0)
                __hip_atomic_store(&flags[jb * FSTR], target + 1,
                                   __ATOMIC_RELEASE, __HIP_MEMORY_SCOPE_AGENT);
        }
        // flush outputs (HBM) once per 8 steps — off the handoff path
        #pragma unroll
        for (int p = 0; p < 8; ++p) {
            int t = t0 + tc8 + p;
            outputs[((size_t)b_e * T + t) * H + hj] = oreg[p];
        }
    }

    cbuf[b_e * H + hj] = creg;
}

// ---------------------------------------------------------------------------
// init h slot 0 in producer-major layout: slot0[j>>3][b][j&7] = h0[b][j]
__global__ __launch_bounds__(256) void init_state(
    const float* __restrict__ h0, const float* __restrict__ c0,
    unsigned short* __restrict__ hb, float* __restrict__ cb)
{
    int i = blockIdx.x * 256 + threadIdx.x;    // 0..65535
    int b = i >> 10, j = i & 1023;
    hb[(size_t)(j >> 3) * 512 + b * 8 + (j & 7)] = f2bf(h0[i]);
    cb[i] = c0[i];
}

__global__ __launch_bounds__(128) void reset_flags(int* __restrict__ flags)
{
    __hip_atomic_store(&flags[threadIdx.x * FSTR], 0,
                       __ATOMIC_RELAXED, __HIP_MEMORY_SCOPE_AGENT);
}

// copy slot TC -> slot 0 (layout-identical dword copy)
__global__ __launch_bounds__(256) void copy_h(
    const unsigned short* __restrict__ src, unsigned short* __restrict__ dst)
{
    int i = blockIdx.x * 256 + threadIdx.x;    // dword index
    ((unsigned*)dst)[i] = ((const unsigned*)src)[i];
}

__global__ __launch_bounds__(256) void finalize(
    const float* __restrict__ outputs, const float* __restrict__ cfin,
    float* __restrict__ outh, float* __restrict__ outc)
{
    int i = blockIdx.x * 256 + threadIdx.x;    // 0..65535
    int b = i >> 10, j = i & 1023;
    outh[i] = outputs[((size_t)b * T + (T - 1)) * H + j];
    outc[i] = cfin[i];
}

// ---------------------------------------------------------------------------
extern "C" void kernel_launch(void* const* d_in, const int* in_sizes, int n_in,
                              void* d_out, int out_size, void* d_ws, size_t ws_size,
                              hipStream_t stream)
{
    const int*   tgt = (const int*)  d_in[0];
    const float* h0  = (const float*)d_in[1];
    const float* c0  = (const float*)d_in[2];
    const float* emb = (const float*)d_in[5];
    const float* Wih = (const float*)d_in[6];
    const float* Whh = (const float*)d_in[7];
    const float* bih = (const float*)d_in[8];
    const float* bhh = (const float*)d_in[9];

    float* out     = (float*)d_out;
    float* outputs = out;                                  // [B][T][H]
    float* out_h   = out + (size_t)B * T * H;
    float* out_c   = out_h + B * H;

    // ws layout — ~56.5 MB
    unsigned short* xproj  = (unsigned short*)d_ws;            // TC*B*G4
    unsigned short* xch    = xproj  + (size_t)TC * B * G4;     // TC*B*H
    unsigned short* wih    = xch    + (size_t)TC * B * H;      // G4*H
    unsigned short* whh    = wih    + (size_t)G4 * H;          // G4*H
    unsigned short* hchain = whh    + (size_t)G4 * H;          // (TC+1)*B*H
    float*          cbuf   = (float*)(hchain + (size_t)(TC + 1) * B * H);
    int*            flags  = (int*)(cbuf + (size_t)B * H);     // NBLK*FSTR

    cast_f32_bf16<<<2048, 256, 0, stream>>>(Wih, wih, (G4 * H) / 8);
    cast_f32_bf16<<<2048, 256, 0, stream>>>(Whh, whh, (G4 * H) / 8);
    init_state<<<(B * H) / 256, 256, 0, stream>>>(h0, c0, hchain, cbuf);
    reset_flags<<<1, NBLK, 0, stream>>>(flags);

    for (int ci = 0; ci < NCH; ++ci) {
        gather_x<<<(TC * B) / 2, 256, 0, stream>>>(tgt, emb, xch, ci * TC);
        gemm_xproj<<<(TC * B / 128) * (G4 / 128), 256, 0, stream>>>(xch, wih, xproj);
        if (ci) copy_h<<<(B * H / 2) / 256, 256, 0, stream>>>(
                    hchain + (size_t)TC * B * H, hchain);
        int t0 = ci * TC;
        void* args[] = { (void*)&xproj, (void*)&whh, (void*)&bih, (void*)&bhh,
                         (void*)&hchain, (void*)&cbuf, (void*)&outputs,
                         (void*)&flags, (void*)&t0 };
        hipLaunchCooperativeKernel((void*)lstm_chunk, dim3(NBLK), dim3(512),
                                   args, 0, stream);
    }
    finalize<<<(B * H) / 256, 256, 0, stream>>>(outputs, cbuf, out_h, out_c);
}

// Round 15
// 2419.266 us; speedup vs baseline: 2.0189x; 1.0168x over previous
//
#include <hip/hip_runtime.h>
#include <hip/hip_bf16.h>
#include <math.h>

#define B    64
#define T    256
#define H    1024
#define G4   4096
#define TC   64           // timesteps per x_proj chunk
#define NCH  (T / TC)
#define NBLK 128          // persistent blocks (8 h-cols each)
#define FSTR 16           // flag stride in ints (64B apart)

typedef __attribute__((ext_vector_type(8))) short bf16x8;
typedef __attribute__((ext_vector_type(4))) float f32x4;

__device__ __forceinline__ unsigned short f2bf(float x) {
    union { float f; unsigned u; } v; v.f = x;
    unsigned r = v.u + 0x7fffu + ((v.u >> 16) & 1u);   // RNE
    return (unsigned short)(r >> 16);
}
__device__ __forceinline__ float bf2f(unsigned short s) {
    union { unsigned u; float f; } v; v.u = ((unsigned)s) << 16;
    return v.f;
}
__device__ __forceinline__ float sigm_f(float x) {
    return 1.f / (1.f + __expf(-x));
}
__device__ __forceinline__ float tanh_f(float x) {
    float e = __expf(2.f * x);
    return (e - 1.f) / (e + 1.f);
}

// ---------------------------------------------------------------------------
__global__ __launch_bounds__(256) void cast_f32_bf16(
    const float* __restrict__ src, unsigned short* __restrict__ dst, int n8)
{
    int i = blockIdx.x * 256 + threadIdx.x;
    if (i >= n8) return;
    const float4* s = (const float4*)(src + (size_t)i * 8);
    float4 a = s[0], b = s[1];
    bf16x8 o;
    o[0] = f2bf(a.x); o[1] = f2bf(a.y); o[2] = f2bf(a.z); o[3] = f2bf(a.w);
    o[4] = f2bf(b.x); o[5] = f2bf(b.y); o[6] = f2bf(b.z); o[7] = f2bf(b.w);
    *(bf16x8*)(dst + (size_t)i * 8) = o;
}

// ---------------------------------------------------------------------------
__global__ __launch_bounds__(256) void gather_x(
    const int* __restrict__ tgt, const float* __restrict__ emb,
    unsigned short* __restrict__ xch, int t0)
{
    int tid = threadIdx.x;
    int r   = blockIdx.x * 2 + (tid >> 7);     // 0..4095
    int c   = (tid & 127) * 8;
    int b   = r & 63, tcc = r >> 6;
    int token = tgt[b * T + t0 + tcc];
    const float4* s = (const float4*)(emb + (size_t)token * H + c);
    float4 x0 = s[0], x1 = s[1];
    bf16x8 o;
    o[0] = f2bf(x0.x); o[1] = f2bf(x0.y); o[2] = f2bf(x0.z); o[3] = f2bf(x0.w);
    o[4] = f2bf(x1.x); o[5] = f2bf(x1.y); o[6] = f2bf(x1.z); o[7] = f2bf(x1.w);
    *(bf16x8*)(xch + (size_t)r * H + c) = o;
}

// ---------------------------------------------------------------------------
// x_proj chunk GEMM (unchanged — proven since round 2)
// ---------------------------------------------------------------------------
__global__ __launch_bounds__(256) void gemm_xproj(
    const unsigned short* __restrict__ A,   // x chunk bf16 [4096][1024]
    const unsigned short* __restrict__ Bt,  // W_ih bf16 [4096][1024]
    unsigned short* __restrict__ C)         // [4096][4096]
{
    __shared__ unsigned short As[128 * 64], Bs[128 * 64];
    const int tid  = threadIdx.x;
    const int brow = (blockIdx.x >> 5) * 128;
    const int bcol = (blockIdx.x & 31) * 128;
    const int w = tid >> 6, lane = tid & 63;
    const int wr = w >> 1, wc = w & 1;
    const int lr = lane & 15, lg = lane >> 4;

    f32x4 acc[4][4] = {};

    for (int kc = 0; kc < H; kc += 64) {
        if (kc) __syncthreads();
        #pragma unroll
        for (int i = 0; i < 4; ++i) {
            int sf  = i * 256 + tid;
            int row = sf >> 3, s = sf & 7;
            int col = kc + s * 8;
            *(bf16x8*)(As + row * 64 + ((s ^ (row & 7)) * 8)) =
                *(const bf16x8*)(A + (size_t)(brow + row) * H + col);
            *(bf16x8*)(Bs + row * 64 + ((s ^ (row & 7)) * 8)) =
                *(const bf16x8*)(Bt + (size_t)(bcol + row) * H + col);
        }
        __syncthreads();
        #pragma unroll
        for (int kk = 0; kk < 2; ++kk) {
            bf16x8 af[4], bv[4];
            #pragma unroll
            for (int m = 0; m < 4; ++m) {
                int row = wr * 64 + m * 16 + lr;
                int s   = kk * 4 + lg;
                af[m] = *(const bf16x8*)(As + row * 64 + ((s ^ (row & 7)) * 8));
            }
            #pragma unroll
            for (int n = 0; n < 4; ++n) {
                int row = wc * 64 + n * 16 + lr;
                int s   = kk * 4 + lg;
                bv[n] = *(const bf16x8*)(Bs + row * 64 + ((s ^ (row & 7)) * 8));
            }
            #pragma unroll
            for (int m = 0; m < 4; ++m)
                #pragma unroll
                for (int n = 0; n < 4; ++n)
                    acc[m][n] = __builtin_amdgcn_mfma_f32_16x16x32_bf16(
                        af[m], bv[n], acc[m][n], 0, 0, 0);
        }
    }
    #pragma unroll
    for (int m = 0; m < 4; ++m)
        #pragma unroll
        for (int n = 0; n < 4; ++n)
            #pragma unroll
            for (int r = 0; r < 4; ++r) {
                int row = brow + wr * 64 + m * 16 + lg * 4 + r;
                int col = bcol + wc * 64 + n * 16 + lr;
                C[(size_t)row * G4 + col] = f2bf(acc[m][n][r]);
            }
}

// ---------------------------------------------------------------------------
// persistent chunk recurrence — r12 (known-good): 128 blocks x 512 thr,
// producer-major hchain, full-line wave-0 publish, same-wave RELEASE flag.
//  * wave = (m-tile 0..3, K-half 0..1), A reused in-register across BOTH
//    n-tiles -> per-block h read 128 KB (no duplicate A rows); partials
//    joined via gst[2] with a 2-way add in the epilogue;
//  * early-start: K-half kh depends only on producers [64kh, 64kh+64) —
//    each wave polls ITS half's 64 flags and goes straight into MFMA with
//    no barrier. 2 block barriers/step (gst-join, hsh-join).
// ---------------------------------------------------------------------------
__global__ __launch_bounds__(512) void lstm_chunk(
    const unsigned short* __restrict__ xproj,  // [TC][B][4096] bf16
    const unsigned short* __restrict__ whh,    // [4096][1024] bf16
    const float* __restrict__ bih, const float* __restrict__ bhh,
    unsigned short* __restrict__ hchain,       // [TC+1][NBLK][64][8] bf16
    float* __restrict__ cbuf,                  // [B][H] f32
    float* __restrict__ outputs,               // [B][T][H] f32
    int* __restrict__ flags,                   // [NBLK*FSTR]
    int t0)
{
    __shared__ bf16x8 Ws[32 * 128];            // 64 KB, swizzled 16B slots
    __shared__ float  gst[2][64][36];          // [kh][batch][v=q*8+jc]
    __shared__ unsigned short hsh[8][72];      // [jc][batch] new h slice

    const int tid = threadIdx.x;
    const int jb  = blockIdx.x;
    const int j0  = jb * 8;

    // stage W_hh slice: rows v = q*8+jc -> global row q*H + j0 + jc
    #pragma unroll
    for (int it = 0; it < 8; ++it) {
        int f = it * 512 + tid;                // 16B-slot id, 0..4095
        int v = f >> 7, s = f & 127;
        int grow = (v >> 3) * H + j0 + (v & 7);
        Ws[v * 128 + (s ^ (v & 7))] =
            *(const bf16x8*)(whh + (size_t)grow * H + s * 8);
    }

    const int w = tid >> 6, lane = tid & 63;
    const int m = w & 3, kh = w >> 2;          // wave = (m-tile, K-half)
    const int lr = lane & 15, lg = lane >> 4;
    const int vx = lr & 7;                     // swizzle key (same both n-tiles)

    // epilogue mapping: all 512 threads, 1 thread = 1 (b, jc) cell
    const int b_e  = tid >> 3;                 // 0..63
    const int jc_e = tid & 7;
    const int hj   = j0 + jc_e;
    float breg[4];
    #pragma unroll
    for (int qq = 0; qq < 4; ++qq)
        breg[qq] = bih[qq * H + hj] + bhh[qq * H + hj];
    float creg = cbuf[b_e * H + hj];
    __syncthreads();

    for (int tc8 = 0; tc8 < TC; tc8 += 8) {
        float oreg[8];
        #pragma unroll
        for (int p = 0; p < 8; ++p) {
            const int tcs    = tc8 + p;
            const int target = t0 + tcs;

            // prefetch x_proj gate values (independent of h)
            float xpv[4];
            #pragma unroll
            for (int qq = 0; qq < 4; ++qq)
                xpv[qq] = bf2f(xproj[((size_t)tcs * B + b_e) * G4
                                     + qq * H + hj]);

            const unsigned short* hc     = hchain + (size_t)tcs * B * H;
            unsigned short*       hn_buf = hchain + (size_t)(tcs + 1) * B * H;

            // per-wave poll of OWN K-half's 64 producers; no barrier after —
            // this wave's MFMA starts as soon as its half is published
            while (true) {
                int fv = __hip_atomic_load(&flags[(kh * 64 + lane) * FSTR],
                            __ATOMIC_RELAXED, __HIP_MEMORY_SCOPE_AGENT);
                if (__all(fv >= target)) break;
                __builtin_amdgcn_s_sleep(1);
            }

            // h @ W_hh^T over this wave's K-half; A reused for both n-tiles
            f32x4 acc0 = {}, acc1 = {};
            #pragma unroll
            for (int ks = 0; ks < 16; ++ks) {
                int s = kh * 64 + ks * 4 + lg;         // K-slice 0..127
                bf16x8 av = *(const bf16x8*)(hc
                    + ((size_t)s * 64 + m * 16 + lr) * 8);
                bf16x8 bw0 = Ws[lr * 128 + (s ^ vx)];
                bf16x8 bw1 = Ws[(16 + lr) * 128 + (s ^ vx)];
                acc0 = __builtin_amdgcn_mfma_f32_16x16x32_bf16(av, bw0, acc0,
                                                               0, 0, 0);
                acc1 = __builtin_amdgcn_mfma_f32_16x16x32_bf16(av, bw1, acc1,
                                                               0, 0, 0);
            }
            #pragma unroll
            for (int r = 0; r < 4; ++r) {
                gst[kh][m * 16 + lg * 4 + r][lr]      = acc0[r];
                gst[kh][m * 16 + lg * 4 + r][16 + lr] = acc1[r];
            }
            __syncthreads();   // barrier A: gst join (both halves)

            // cell epilogue: 1 thread = 1 (b, jc) cell; h slice -> hsh LDS
            {
                float g[4];
                #pragma unroll
                for (int qq = 0; qq < 4; ++qq)
                    g[qq] = gst[0][b_e][qq * 8 + jc_e]
                          + gst[1][b_e][qq * 8 + jc_e]
                          + breg[qq] + xpv[qq];
                float ig = sigm_f(g[0]);
                float fg = sigm_f(g[1]);
                float gg = tanh_f(g[2]);
                float og = sigm_f(g[3]);
                float cn = fg * creg + ig * gg;
                float hnv = og * tanh_f(cn);
                creg = cn;
                oreg[p] = hnv;
                hsh[jc_e][b_e] = f2bf(hnv);
            }
            __syncthreads();   // barrier B: hsh join

            // wave 0: publish block's contiguous 1KB slice (16 full lines),
            // then RELEASE flag (orders wave-0 publish stores — same wave)
            if (tid < 64) {
                union { bf16x8 v; unsigned long long u[2]; } pk;
                #pragma unroll
                for (int i = 0; i < 8; ++i)
                    pk.v[i] = (short)hsh[i][tid];
                unsigned long long* dst = (unsigned long long*)(hn_buf
                    + ((size_t)jb * 64 + tid) * 8);
                __hip_atomic_store(dst,     pk.u[0], __ATOMIC_RELAXED,
                                   __HIP_MEMORY_SCOPE_AGENT);
                __hip_atomic_store(dst + 1, pk.u[1], __ATOMIC_RELAXED,
                                   __HIP_MEMORY_SCOPE_AGENT);
            }
            if (tid == 0)
                __hip_atomic_store(&flags[jb * FSTR], target + 1,
                                   __ATOMIC_RELEASE, __HIP_MEMORY_SCOPE_AGENT);
        }
        // flush outputs (HBM) once per 8 steps — off the handoff path
        #pragma unroll
        for (int p = 0; p < 8; ++p) {
            int t = t0 + tc8 + p;
            outputs[((size_t)b_e * T + t) * H + hj] = oreg[p];
        }
    }

    cbuf[b_e * H + hj] = creg;
}

// ---------------------------------------------------------------------------
// init h slot 0 in producer-major layout: slot0[j>>3][b][j&7] = h0[b][j]
__global__ __launch_bounds__(256) void init_state(
    const float* __restrict__ h0, const float* __restrict__ c0,
    unsigned short* __restrict__ hb, float* __restrict__ cb)
{
    int i = blockIdx.x * 256 + threadIdx.x;    // 0..65535
    int b = i >> 10, j = i & 1023;
    hb[(size_t)(j >> 3) * 512 + b * 8 + (j & 7)] = f2bf(h0[i]);
    cb[i] = c0[i];
}

__global__ __launch_bounds__(128) void reset_flags(int* __restrict__ flags)
{
    __hip_atomic_store(&flags[threadIdx.x * FSTR], 0,
                       __ATOMIC_RELAXED, __HIP_MEMORY_SCOPE_AGENT);
}

// copy slot TC -> slot 0 (layout-identical dword copy)
__global__ __launch_bounds__(256) void copy_h(
    const unsigned short* __restrict__ src, unsigned short* __restrict__ dst)
{
    int i = blockIdx.x * 256 + threadIdx.x;    // dword index
    ((unsigned*)dst)[i] = ((const unsigned*)src)[i];
}

__global__ __launch_bounds__(256) void finalize(
    const float* __restrict__ outputs, const float* __restrict__ cfin,
    float* __restrict__ outh, float* __restrict__ outc)
{
    int i = blockIdx.x * 256 + threadIdx.x;    // 0..65535
    int b = i >> 10, j = i & 1023;
    outh[i] = outputs[((size_t)b * T + (T - 1)) * H + j];
    outc[i] = cfin[i];
}

// ---------------------------------------------------------------------------
extern "C" void kernel_launch(void* const* d_in, const int* in_sizes, int n_in,
                              void* d_out, int out_size, void* d_ws, size_t ws_size,
                              hipStream_t stream)
{
    const int*   tgt = (const int*)  d_in[0];
    const float* h0  = (const float*)d_in[1];
    const float* c0  = (const float*)d_in[2];
    const float* emb = (const float*)d_in[5];
    const float* Wih = (const float*)d_in[6];
    const float* Whh = (const float*)d_in[7];
    const float* bih = (const float*)d_in[8];
    const float* bhh = (const float*)d_in[9];

    float* out     = (float*)d_out;
    float* outputs = out;                                  // [B][T][H]
    float* out_h   = out + (size_t)B * T * H;
    float* out_c   = out_h + B * H;

    // ws layout — ~56.5 MB
    unsigned short* xproj  = (unsigned short*)d_ws;            // TC*B*G4
    unsigned short* xch    = xproj  + (size_t)TC * B * G4;     // TC*B*H
    unsigned short* wih    = xch    + (size_t)TC * B * H;      // G4*H
    unsigned short* whh    = wih    + (size_t)G4 * H;          // G4*H
    unsigned short* hchain = whh    + (size_t)G4 * H;          // (TC+1)*B*H
    float*          cbuf   = (float*)(hchain + (size_t)(TC + 1) * B * H);
    int*            flags  = (int*)(cbuf + (size_t)B * H);     // NBLK*FSTR

    cast_f32_bf16<<<2048, 256, 0, stream>>>(Wih, wih, (G4 * H) / 8);
    cast_f32_bf16<<<2048, 256, 0, stream>>>(Whh, whh, (G4 * H) / 8);
    init_state<<<(B * H) / 256, 256, 0, stream>>>(h0, c0, hchain, cbuf);
    reset_flags<<<1, NBLK, 0, stream>>>(flags);

    for (int ci = 0; ci < NCH; ++ci) {
        gather_x<<<(TC * B) / 2, 256, 0, stream>>>(tgt, emb, xch, ci * TC);
        gemm_xproj<<<(TC * B / 128) * (G4 / 128), 256, 0, stream>>>(xch, wih, xproj);
        if (ci) copy_h<<<(B * H / 2) / 256, 256, 0, stream>>>(
                    hchain + (size_t)TC * B * H, hchain);
        int t0 = ci * TC;
        void* args[] = { (void*)&xproj, (void*)&whh, (void*)&bih, (void*)&bhh,
                         (void*)&hchain, (void*)&cbuf, (void*)&outputs,
                         (void*)&flags, (void*)&t0 };
        hipLaunchCooperativeKernel((void*)lstm_chunk, dim3(NBLK), dim3(512),
                                   args, 0, stream);
    }
    finalize<<<(B * H) / 256, 256, 0, stream>>>(outputs, cbuf, out_h, out_c);
}

// Round 16
// 1581.402 us; speedup vs baseline: 3.0885x; 1.5298x over previous
//
#include <hip/hip_runtime.h>
#include <hip/hip_bf16.h>
#include <math.h>

#define B    64
#define T    256
#define H    1024
#define G4   4096
#define TC   64           // timesteps per x_proj chunk
#define NCH  (T / TC)
#define NBLK 128          // persistent blocks (8 h-cols each)
#define FSTR 16           // flag stride in ints (64B apart)

typedef __attribute__((ext_vector_type(8))) short bf16x8;
typedef __attribute__((ext_vector_type(4))) float f32x4;

__device__ __forceinline__ unsigned short f2bf(float x) {
    union { float f; unsigned u; } v; v.f = x;
    unsigned r = v.u + 0x7fffu + ((v.u >> 16) & 1u);   // RNE
    return (unsigned short)(r >> 16);
}
__device__ __forceinline__ float bf2f(unsigned short s) {
    union { unsigned u; float f; } v; v.u = ((unsigned)s) << 16;
    return v.f;
}
__device__ __forceinline__ float sigm_f(float x) {
    return 1.f / (1.f + __expf(-x));
}
__device__ __forceinline__ float tanh_f(float x) {
    float e = __expf(2.f * x);
    return (e - 1.f) / (e + 1.f);
}

// ---------------------------------------------------------------------------
__global__ __launch_bounds__(256) void cast_f32_bf16(
    const float* __restrict__ src, unsigned short* __restrict__ dst, int n8)
{
    int i = blockIdx.x * 256 + threadIdx.x;
    if (i >= n8) return;
    const float4* s = (const float4*)(src + (size_t)i * 8);
    float4 a = s[0], b = s[1];
    bf16x8 o;
    o[0] = f2bf(a.x); o[1] = f2bf(a.y); o[2] = f2bf(a.z); o[3] = f2bf(a.w);
    o[4] = f2bf(b.x); o[5] = f2bf(b.y); o[6] = f2bf(b.z); o[7] = f2bf(b.w);
    *(bf16x8*)(dst + (size_t)i * 8) = o;
}

// ---------------------------------------------------------------------------
__global__ __launch_bounds__(256) void gather_x(
    const int* __restrict__ tgt, const float* __restrict__ emb,
    unsigned short* __restrict__ xch, int t0)
{
    int tid = threadIdx.x;
    int r   = blockIdx.x * 2 + (tid >> 7);     // 0..4095
    int c   = (tid & 127) * 8;
    int b   = r & 63, tcc = r >> 6;
    int token = tgt[b * T + t0 + tcc];
    const float4* s = (const float4*)(emb + (size_t)token * H + c);
    float4 x0 = s[0], x1 = s[1];
    bf16x8 o;
    o[0] = f2bf(x0.x); o[1] = f2bf(x0.y); o[2] = f2bf(x0.z); o[3] = f2bf(x0.w);
    o[4] = f2bf(x1.x); o[5] = f2bf(x1.y); o[6] = f2bf(x1.z); o[7] = f2bf(x1.w);
    *(bf16x8*)(xch + (size_t)r * H + c) = o;
}

// ---------------------------------------------------------------------------
// x_proj chunk GEMM (unchanged — proven since round 2)
// ---------------------------------------------------------------------------
__global__ __launch_bounds__(256) void gemm_xproj(
    const unsigned short* __restrict__ A,   // x chunk bf16 [4096][1024]
    const unsigned short* __restrict__ Bt,  // W_ih bf16 [4096][1024]
    unsigned short* __restrict__ C)         // [4096][4096]
{
    __shared__ unsigned short As[128 * 64], Bs[128 * 64];
    const int tid  = threadIdx.x;
    const int brow = (blockIdx.x >> 5) * 128;
    const int bcol = (blockIdx.x & 31) * 128;
    const int w = tid >> 6, lane = tid & 63;
    const int wr = w >> 1, wc = w & 1;
    const int lr = lane & 15, lg = lane >> 4;

    f32x4 acc[4][4] = {};

    for (int kc = 0; kc < H; kc += 64) {
        if (kc) __syncthreads();
        #pragma unroll
        for (int i = 0; i < 4; ++i) {
            int sf  = i * 256 + tid;
            int row = sf >> 3, s = sf & 7;
            int col = kc + s * 8;
            *(bf16x8*)(As + row * 64 + ((s ^ (row & 7)) * 8)) =
                *(const bf16x8*)(A + (size_t)(brow + row) * H + col);
            *(bf16x8*)(Bs + row * 64 + ((s ^ (row & 7)) * 8)) =
                *(const bf16x8*)(Bt + (size_t)(bcol + row) * H + col);
        }
        __syncthreads();
        #pragma unroll
        for (int kk = 0; kk < 2; ++kk) {
            bf16x8 af[4], bv[4];
            #pragma unroll
            for (int m = 0; m < 4; ++m) {
                int row = wr * 64 + m * 16 + lr;
                int s   = kk * 4 + lg;
                af[m] = *(const bf16x8*)(As + row * 64 + ((s ^ (row & 7)) * 8));
            }
            #pragma unroll
            for (int n = 0; n < 4; ++n) {
                int row = wc * 64 + n * 16 + lr;
                int s   = kk * 4 + lg;
                bv[n] = *(const bf16x8*)(Bs + row * 64 + ((s ^ (row & 7)) * 8));
            }
            #pragma unroll
            for (int m = 0; m < 4; ++m)
                #pragma unroll
                for (int n = 0; n < 4; ++n)
                    acc[m][n] = __builtin_amdgcn_mfma_f32_16x16x32_bf16(
                        af[m], bv[n], acc[m][n], 0, 0, 0);
        }
    }
    #pragma unroll
    for (int m = 0; m < 4; ++m)
        #pragma unroll
        for (int n = 0; n < 4; ++n)
            #pragma unroll
            for (int r = 0; r < 4; ++r) {
                int row = brow + wr * 64 + m * 16 + lg * 4 + r;
                int col = bcol + wc * 64 + n * 16 + lr;
                C[(size_t)row * G4 + col] = f2bf(acc[m][n][r]);
            }
}

// ---------------------------------------------------------------------------
// persistent chunk recurrence — r12/r15 structure (known-good sync: block
// barriers + same-wave publish->drain->flag) with two safe tweaks:
//  * flag store is RELAXED, ordered by an explicit in-wave
//    `s_waitcnt vmcnt(0)` after the wave-0 publish (r5/r7/r8-proven pattern).
//    This avoids the agent-scope RELEASE lowering (vmcnt drain + L2
//    writeback) that would flush dirty `outputs` lines to HBM on every
//    step's critical path;
//  * s_setprio(1) around the load+MFMA region (waves are at different
//    phases after the per-half early-start poll — the regime where setprio
//    measurably helps).
// ---------------------------------------------------------------------------
__global__ __launch_bounds__(512) void lstm_chunk(
    const unsigned short* __restrict__ xproj,  // [TC][B][4096] bf16
    const unsigned short* __restrict__ whh,    // [4096][1024] bf16
    const float* __restrict__ bih, const float* __restrict__ bhh,
    unsigned short* __restrict__ hchain,       // [TC+1][NBLK][64][8] bf16
    float* __restrict__ cbuf,                  // [B][H] f32
    float* __restrict__ outputs,               // [B][T][H] f32
    int* __restrict__ flags,                   // [NBLK*FSTR]
    int t0)
{
    __shared__ bf16x8 Ws[32 * 128];            // 64 KB, swizzled 16B slots
    __shared__ float  gst[2][64][36];          // [kh][batch][v=q*8+jc]
    __shared__ unsigned short hsh[8][72];      // [jc][batch] new h slice

    const int tid = threadIdx.x;
    const int jb  = blockIdx.x;
    const int j0  = jb * 8;

    // stage W_hh slice: rows v = q*8+jc -> global row q*H + j0 + jc
    #pragma unroll
    for (int it = 0; it < 8; ++it) {
        int f = it * 512 + tid;                // 16B-slot id, 0..4095
        int v = f >> 7, s = f & 127;
        int grow = (v >> 3) * H + j0 + (v & 7);
        Ws[v * 128 + (s ^ (v & 7))] =
            *(const bf16x8*)(whh + (size_t)grow * H + s * 8);
    }

    const int w = tid >> 6, lane = tid & 63;
    const int m = w & 3, kh = w >> 2;          // wave = (m-tile, K-half)
    const int lr = lane & 15, lg = lane >> 4;
    const int vx = lr & 7;                     // swizzle key (same both n-tiles)

    // epilogue mapping: all 512 threads, 1 thread = 1 (b, jc) cell
    const int b_e  = tid >> 3;                 // 0..63
    const int jc_e = tid & 7;
    const int hj   = j0 + jc_e;
    float breg[4];
    #pragma unroll
    for (int qq = 0; qq < 4; ++qq)
        breg[qq] = bih[qq * H + hj] + bhh[qq * H + hj];
    float creg = cbuf[b_e * H + hj];
    __syncthreads();

    for (int tc8 = 0; tc8 < TC; tc8 += 8) {
        float oreg[8];
        #pragma unroll
        for (int p = 0; p < 8; ++p) {
            const int tcs    = tc8 + p;
            const int target = t0 + tcs;

            // prefetch x_proj gate values (independent of h)
            float xpv[4];
            #pragma unroll
            for (int qq = 0; qq < 4; ++qq)
                xpv[qq] = bf2f(xproj[((size_t)tcs * B + b_e) * G4
                                     + qq * H + hj]);

            const unsigned short* hc     = hchain + (size_t)tcs * B * H;
            unsigned short*       hn_buf = hchain + (size_t)(tcs + 1) * B * H;

            // per-wave poll of OWN K-half's 64 producers; no barrier after —
            // this wave's MFMA starts as soon as its half is published
            while (true) {
                int fv = __hip_atomic_load(&flags[(kh * 64 + lane) * FSTR],
                            __ATOMIC_RELAXED, __HIP_MEMORY_SCOPE_AGENT);
                if (__all(fv >= target)) break;
                __builtin_amdgcn_s_sleep(1);
            }

            // h @ W_hh^T over this wave's K-half; A reused for both n-tiles
            __builtin_amdgcn_s_setprio(1);
            f32x4 acc0 = {}, acc1 = {};
            #pragma unroll
            for (int ks = 0; ks < 16; ++ks) {
                int s = kh * 64 + ks * 4 + lg;         // K-slice 0..127
                bf16x8 av = *(const bf16x8*)(hc
                    + ((size_t)s * 64 + m * 16 + lr) * 8);
                bf16x8 bw0 = Ws[lr * 128 + (s ^ vx)];
                bf16x8 bw1 = Ws[(16 + lr) * 128 + (s ^ vx)];
                acc0 = __builtin_amdgcn_mfma_f32_16x16x32_bf16(av, bw0, acc0,
                                                               0, 0, 0);
                acc1 = __builtin_amdgcn_mfma_f32_16x16x32_bf16(av, bw1, acc1,
                                                               0, 0, 0);
            }
            __builtin_amdgcn_s_setprio(0);
            #pragma unroll
            for (int r = 0; r < 4; ++r) {
                gst[kh][m * 16 + lg * 4 + r][lr]      = acc0[r];
                gst[kh][m * 16 + lg * 4 + r][16 + lr] = acc1[r];
            }
            __syncthreads();   // barrier A: gst join (both halves)

            // cell epilogue: 1 thread = 1 (b, jc) cell; h slice -> hsh LDS
            {
                float g[4];
                #pragma unroll
                for (int qq = 0; qq < 4; ++qq)
                    g[qq] = gst[0][b_e][qq * 8 + jc_e]
                          + gst[1][b_e][qq * 8 + jc_e]
                          + breg[qq] + xpv[qq];
                float ig = sigm_f(g[0]);
                float fg = sigm_f(g[1]);
                float gg = tanh_f(g[2]);
                float og = sigm_f(g[3]);
                float cn = fg * creg + ig * gg;
                float hnv = og * tanh_f(cn);
                creg = cn;
                oreg[p] = hnv;
                hsh[jc_e][b_e] = f2bf(hnv);
            }
            __syncthreads();   // barrier B: hsh join

            // wave 0: publish block's contiguous 1KB slice (16 full lines),
            // explicit in-wave vmcnt drain, then RELAXED flag — same-wave
            // ordering, no agent-release L2 writeback on the critical path
            if (tid < 64) {
                union { bf16x8 v; unsigned long long u[2]; } pk;
                #pragma unroll
                for (int i = 0; i < 8; ++i)
                    pk.v[i] = (short)hsh[i][tid];
                unsigned long long* dst = (unsigned long long*)(hn_buf
                    + ((size_t)jb * 64 + tid) * 8);
                __hip_atomic_store(dst,     pk.u[0], __ATOMIC_RELAXED,
                                   __HIP_MEMORY_SCOPE_AGENT);
                __hip_atomic_store(dst + 1, pk.u[1], __ATOMIC_RELAXED,
                                   __HIP_MEMORY_SCOPE_AGENT);
                asm volatile("s_waitcnt vmcnt(0)" ::: "memory");
                if (lane == 0)
                    __hip_atomic_store(&flags[jb * FSTR], target + 1,
                                       __ATOMIC_RELAXED,
                                       __HIP_MEMORY_SCOPE_AGENT);
            }
        }
        // flush outputs (HBM) once per 8 steps — off the handoff path
        #pragma unroll
        for (int p = 0; p < 8; ++p) {
            int t = t0 + tc8 + p;
            outputs[((size_t)b_e * T + t) * H + hj] = oreg[p];
        }
    }

    cbuf[b_e * H + hj] = creg;
}

// ---------------------------------------------------------------------------
// init h slot 0 in producer-major layout: slot0[j>>3][b][j&7] = h0[b][j]
__global__ __launch_bounds__(256) void init_state(
    const float* __restrict__ h0, const float* __restrict__ c0,
    unsigned short* __restrict__ hb, float* __restrict__ cb)
{
    int i = blockIdx.x * 256 + threadIdx.x;    // 0..65535
    int b = i >> 10, j = i & 1023;
    hb[(size_t)(j >> 3) * 512 + b * 8 + (j & 7)] = f2bf(h0[i]);
    cb[i] = c0[i];
}

__global__ __launch_bounds__(128) void reset_flags(int* __restrict__ flags)
{
    __hip_atomic_store(&flags[threadIdx.x * FSTR], 0,
                       __ATOMIC_RELAXED, __HIP_MEMORY_SCOPE_AGENT);
}

// copy slot TC -> slot 0 (layout-identical dword copy)
__global__ __launch_bounds__(256) void copy_h(
    const unsigned short* __restrict__ src, unsigned short* __restrict__ dst)
{
    int i = blockIdx.x * 256 + threadIdx.x;    // dword index
    ((unsigned*)dst)[i] = ((const unsigned*)src)[i];
}

__global__ __launch_bounds__(256) void finalize(
    const float* __restrict__ outputs, const float* __restrict__ cfin,
    float* __restrict__ outh, float* __restrict__ outc)
{
    int i = blockIdx.x * 256 + threadIdx.x;    // 0..65535
    int b = i >> 10, j = i & 1023;
    outh[i] = outputs[((size_t)b * T + (T - 1)) * H + j];
    outc[i] = cfin[i];
}

// ---------------------------------------------------------------------------
extern "C" void kernel_launch(void* const* d_in, const int* in_sizes, int n_in,
                              void* d_out, int out_size, void* d_ws, size_t ws_size,
                              hipStream_t stream)
{
    const int*   tgt = (const int*)  d_in[0];
    const float* h0  = (const float*)d_in[1];
    const float* c0  = (const float*)d_in[2];
    const float* emb = (const float*)d_in[5];
    const float* Wih = (const float*)d_in[6];
    const float* Whh = (const float*)d_in[7];
    const float* bih = (const float*)d_in[8];
    const float* bhh = (const float*)d_in[9];

    float* out     = (float*)d_out;
    float* outputs = out;                                  // [B][T][H]
    float* out_h   = out + (size_t)B * T * H;
    float* out_c   = out_h + B * H;

    // ws layout — ~56.5 MB
    unsigned short* xproj  = (unsigned short*)d_ws;            // TC*B*G4
    unsigned short* xch    = xproj  + (size_t)TC * B * G4;     // TC*B*H
    unsigned short* wih    = xch    + (size_t)TC * B * H;      // G4*H
    unsigned short* whh    = wih    + (size_t)G4 * H;          // G4*H
    unsigned short* hchain = whh    + (size_t)G4 * H;          // (TC+1)*B*H
    float*          cbuf   = (float*)(hchain + (size_t)(TC + 1) * B * H);
    int*            flags  = (int*)(cbuf + (size_t)B * H);     // NBLK*FSTR

    cast_f32_bf16<<<2048, 256, 0, stream>>>(Wih, wih, (G4 * H) / 8);
    cast_f32_bf16<<<2048, 256, 0, stream>>>(Whh, whh, (G4 * H) / 8);
    init_state<<<(B * H) / 256, 256, 0, stream>>>(h0, c0, hchain, cbuf);
    reset_flags<<<1, NBLK, 0, stream>>>(flags);

    for (int ci = 0; ci < NCH; ++ci) {
        gather_x<<<(TC * B) / 2, 256, 0, stream>>>(tgt, emb, xch, ci * TC);
        gemm_xproj<<<(TC * B / 128) * (G4 / 128), 256, 0, stream>>>(xch, wih, xproj);
        if (ci) copy_h<<<(B * H / 2) / 256, 256, 0, stream>>>(
                    hchain + (size_t)TC * B * H, hchain);
        int t0 = ci * TC;
        void* args[] = { (void*)&xproj, (void*)&whh, (void*)&bih, (void*)&bhh,
                         (void*)&hchain, (void*)&cbuf, (void*)&outputs,
                         (void*)&flags, (void*)&t0 };
        hipLaunchCooperativeKernel((void*)lstm_chunk, dim3(NBLK), dim3(512),
                                   args, 0, stream);
    }
    finalize<<<(B * H) / 256, 256, 0, stream>>>(outputs, cbuf, out_h, out_c);
}

// Round 17
// 1282.799 us; speedup vs baseline: 3.8075x; 1.2328x over previous
//
#include <hip/hip_runtime.h>
#include <hip/hip_bf16.h>
#include <math.h>

#define B    64
#define T    256
#define H    1024
#define G4   4096
#define TC   64           // timesteps per x_proj chunk
#define NCH  (T / TC)
#define NBLK 128          // persistent blocks (8 h-cols each)
#define FSTR 16           // flag stride in ints (64B apart)

typedef __attribute__((ext_vector_type(8))) short bf16x8;
typedef __attribute__((ext_vector_type(4))) float f32x4;

__device__ __forceinline__ unsigned short f2bf(float x) {
    union { float f; unsigned u; } v; v.f = x;
    unsigned r = v.u + 0x7fffu + ((v.u >> 16) & 1u);   // RNE
    return (unsigned short)(r >> 16);
}
__device__ __forceinline__ float bf2f(unsigned short s) {
    union { unsigned u; float f; } v; v.u = ((unsigned)s) << 16;
    return v.f;
}
__device__ __forceinline__ float sigm_f(float x) {
    return 1.f / (1.f + __expf(-x));
}
__device__ __forceinline__ float tanh_f(float x) {
    float e = __expf(2.f * x);
    return (e - 1.f) / (e + 1.f);
}

// ---------------------------------------------------------------------------
__global__ __launch_bounds__(256) void cast_f32_bf16(
    const float* __restrict__ src, unsigned short* __restrict__ dst, int n8)
{
    int i = blockIdx.x * 256 + threadIdx.x;
    if (i >= n8) return;
    const float4* s = (const float4*)(src + (size_t)i * 8);
    float4 a = s[0], b = s[1];
    bf16x8 o;
    o[0] = f2bf(a.x); o[1] = f2bf(a.y); o[2] = f2bf(a.z); o[3] = f2bf(a.w);
    o[4] = f2bf(b.x); o[5] = f2bf(b.y); o[6] = f2bf(b.z); o[7] = f2bf(b.w);
    *(bf16x8*)(dst + (size_t)i * 8) = o;
}

// ---------------------------------------------------------------------------
__global__ __launch_bounds__(256) void gather_x(
    const int* __restrict__ tgt, const float* __restrict__ emb,
    unsigned short* __restrict__ xch, int t0)
{
    int tid = threadIdx.x;
    int r   = blockIdx.x * 2 + (tid >> 7);     // 0..4095
    int c   = (tid & 127) * 8;
    int b   = r & 63, tcc = r >> 6;
    int token = tgt[b * T + t0 + tcc];
    const float4* s = (const float4*)(emb + (size_t)token * H + c);
    float4 x0 = s[0], x1 = s[1];
    bf16x8 o;
    o[0] = f2bf(x0.x); o[1] = f2bf(x0.y); o[2] = f2bf(x0.z); o[3] = f2bf(x0.w);
    o[4] = f2bf(x1.x); o[5] = f2bf(x1.y); o[6] = f2bf(x1.z); o[7] = f2bf(x1.w);
    *(bf16x8*)(xch + (size_t)r * H + c) = o;
}

// ---------------------------------------------------------------------------
// x_proj chunk GEMM (unchanged — proven since round 2)
// ---------------------------------------------------------------------------
__global__ __launch_bounds__(256) void gemm_xproj(
    const unsigned short* __restrict__ A,   // x chunk bf16 [4096][1024]
    const unsigned short* __restrict__ Bt,  // W_ih bf16 [4096][1024]
    unsigned short* __restrict__ C)         // [4096][4096]
{
    __shared__ unsigned short As[128 * 64], Bs[128 * 64];
    const int tid  = threadIdx.x;
    const int brow = (blockIdx.x >> 5) * 128;
    const int bcol = (blockIdx.x & 31) * 128;
    const int w = tid >> 6, lane = tid & 63;
    const int wr = w >> 1, wc = w & 1;
    const int lr = lane & 15, lg = lane >> 4;

    f32x4 acc[4][4] = {};

    for (int kc = 0; kc < H; kc += 64) {
        if (kc) __syncthreads();
        #pragma unroll
        for (int i = 0; i < 4; ++i) {
            int sf  = i * 256 + tid;
            int row = sf >> 3, s = sf & 7;
            int col = kc + s * 8;
            *(bf16x8*)(As + row * 64 + ((s ^ (row & 7)) * 8)) =
                *(const bf16x8*)(A + (size_t)(brow + row) * H + col);
            *(bf16x8*)(Bs + row * 64 + ((s ^ (row & 7)) * 8)) =
                *(const bf16x8*)(Bt + (size_t)(bcol + row) * H + col);
        }
        __syncthreads();
        #pragma unroll
        for (int kk = 0; kk < 2; ++kk) {
            bf16x8 af[4], bv[4];
            #pragma unroll
            for (int m = 0; m < 4; ++m) {
                int row = wr * 64 + m * 16 + lr;
                int s   = kk * 4 + lg;
                af[m] = *(const bf16x8*)(As + row * 64 + ((s ^ (row & 7)) * 8));
            }
            #pragma unroll
            for (int n = 0; n < 4; ++n) {
                int row = wc * 64 + n * 16 + lr;
                int s   = kk * 4 + lg;
                bv[n] = *(const bf16x8*)(Bs + row * 64 + ((s ^ (row & 7)) * 8));
            }
            #pragma unroll
            for (int m = 0; m < 4; ++m)
                #pragma unroll
                for (int n = 0; n < 4; ++n)
                    acc[m][n] = __builtin_amdgcn_mfma_f32_16x16x32_bf16(
                        af[m], bv[n], acc[m][n], 0, 0, 0);
        }
    }
    #pragma unroll
    for (int m = 0; m < 4; ++m)
        #pragma unroll
        for (int n = 0; n < 4; ++n)
            #pragma unroll
            for (int r = 0; r < 4; ++r) {
                int row = brow + wr * 64 + m * 16 + lg * 4 + r;
                int col = bcol + wc * 64 + n * 16 + lr;
                C[(size_t)row * G4 + col] = f2bf(acc[m][n][r]);
            }
}

// ---------------------------------------------------------------------------
// persistent chunk recurrence — r16 structure with the wave-0 serial pack
// tail removed: epilogue threads publish their own cells DIRECTLY from
// registers (shfl-pair-packed dwords; wave w's 8 batches = 128B = 2 full
// lines), then ONE barrier (compiler drains vmcnt before s_barrier) and a
// relaxed flag from tid 0 — the r5–r9-proven multi-wave-publish pattern.
// hsh LDS array and the barrier-B→wave0-pack→drain tail are gone.
// ---------------------------------------------------------------------------
__global__ __launch_bounds__(512) void lstm_chunk(
    const unsigned short* __restrict__ xproj,  // [TC][B][4096] bf16
    const unsigned short* __restrict__ whh,    // [4096][1024] bf16
    const float* __restrict__ bih, const float* __restrict__ bhh,
    unsigned short* __restrict__ hchain,       // [TC+1][NBLK][64][8] bf16
    float* __restrict__ cbuf,                  // [B][H] f32
    float* __restrict__ outputs,               // [B][T][H] f32
    int* __restrict__ flags,                   // [NBLK*FSTR]
    int t0)
{
    __shared__ bf16x8 Ws[32 * 128];            // 64 KB, swizzled 16B slots
    __shared__ float  gst[2][64][36];          // [kh][batch][v=q*8+jc]

    const int tid = threadIdx.x;
    const int jb  = blockIdx.x;
    const int j0  = jb * 8;

    // stage W_hh slice: rows v = q*8+jc -> global row q*H + j0 + jc
    #pragma unroll
    for (int it = 0; it < 8; ++it) {
        int f = it * 512 + tid;                // 16B-slot id, 0..4095
        int v = f >> 7, s = f & 127;
        int grow = (v >> 3) * H + j0 + (v & 7);
        Ws[v * 128 + (s ^ (v & 7))] =
            *(const bf16x8*)(whh + (size_t)grow * H + s * 8);
    }

    const int w = tid >> 6, lane = tid & 63;
    const int m = w & 3, kh = w >> 2;          // wave = (m-tile, K-half)
    const int lr = lane & 15, lg = lane >> 4;
    const int vx = lr & 7;                     // swizzle key (same both n-tiles)

    // epilogue mapping: all 512 threads, 1 thread = 1 (b, jc) cell
    const int b_e  = tid >> 3;                 // 0..63 (wave w: 8 consecutive)
    const int jc_e = tid & 7;
    const int hj   = j0 + jc_e;
    float breg[4];
    #pragma unroll
    for (int qq = 0; qq < 4; ++qq)
        breg[qq] = bih[qq * H + hj] + bhh[qq * H + hj];
    float creg = cbuf[b_e * H + hj];
    __syncthreads();

    for (int tc8 = 0; tc8 < TC; tc8 += 8) {
        float oreg[8];
        #pragma unroll
        for (int p = 0; p < 8; ++p) {
            const int tcs    = tc8 + p;
            const int target = t0 + tcs;

            // prefetch x_proj gate values (independent of h)
            float xpv[4];
            #pragma unroll
            for (int qq = 0; qq < 4; ++qq)
                xpv[qq] = bf2f(xproj[((size_t)tcs * B + b_e) * G4
                                     + qq * H + hj]);

            const unsigned short* hc     = hchain + (size_t)tcs * B * H;
            unsigned short*       hn_buf = hchain + (size_t)(tcs + 1) * B * H;

            // per-wave poll of OWN K-half's 64 producers; no barrier after —
            // this wave's MFMA starts as soon as its half is published
            while (true) {
                int fv = __hip_atomic_load(&flags[(kh * 64 + lane) * FSTR],
                            __ATOMIC_RELAXED, __HIP_MEMORY_SCOPE_AGENT);
                if (__all(fv >= target)) break;
                __builtin_amdgcn_s_sleep(1);
            }

            // h @ W_hh^T over this wave's K-half; A reused for both n-tiles
            __builtin_amdgcn_s_setprio(1);
            f32x4 acc0 = {}, acc1 = {};
            #pragma unroll
            for (int ks = 0; ks < 16; ++ks) {
                int s = kh * 64 + ks * 4 + lg;         // K-slice 0..127
                bf16x8 av = *(const bf16x8*)(hc
                    + ((size_t)s * 64 + m * 16 + lr) * 8);
                bf16x8 bw0 = Ws[lr * 128 + (s ^ vx)];
                bf16x8 bw1 = Ws[(16 + lr) * 128 + (s ^ vx)];
                acc0 = __builtin_amdgcn_mfma_f32_16x16x32_bf16(av, bw0, acc0,
                                                               0, 0, 0);
                acc1 = __builtin_amdgcn_mfma_f32_16x16x32_bf16(av, bw1, acc1,
                                                               0, 0, 0);
            }
            __builtin_amdgcn_s_setprio(0);
            #pragma unroll
            for (int r = 0; r < 4; ++r) {
                gst[kh][m * 16 + lg * 4 + r][lr]      = acc0[r];
                gst[kh][m * 16 + lg * 4 + r][16 + lr] = acc1[r];
            }
            __syncthreads();   // barrier A: gst join (both halves)

            // cell epilogue: 1 thread = 1 (b, jc) cell; publish DIRECT from
            // registers (shfl-pair pack; wave's 8 rows = 2 full 64B lines)
            {
                float g[4];
                #pragma unroll
                for (int qq = 0; qq < 4; ++qq)
                    g[qq] = gst[0][b_e][qq * 8 + jc_e]
                          + gst[1][b_e][qq * 8 + jc_e]
                          + breg[qq] + xpv[qq];
                float ig = sigm_f(g[0]);
                float fg = sigm_f(g[1]);
                float gg = tanh_f(g[2]);
                float og = sigm_f(g[3]);
                float cn = fg * creg + ig * gg;
                float hnv = og * tanh_f(cn);
                creg = cn;
                oreg[p] = hnv;
                unsigned my = (unsigned)f2bf(hnv);
                unsigned ot = __shfl_xor(my, 1);
                if ((lane & 1) == 0) {
                    unsigned u = my | (ot << 16);
                    unsigned* dst = (unsigned*)(hn_buf
                        + (size_t)(jb * 64 + b_e) * 8 + jc_e);  // jc_e even
                    __hip_atomic_store(dst, u, __ATOMIC_RELAXED,
                                       __HIP_MEMORY_SCOPE_AGENT);
                }
            }
            __syncthreads();   // barrier B: drains ALL waves' publish stores
                               // (compiler emits vmcnt(0) before s_barrier)

            if (tid == 0)
                __hip_atomic_store(&flags[jb * FSTR], target + 1,
                                   __ATOMIC_RELAXED, __HIP_MEMORY_SCOPE_AGENT);
        }
        // flush outputs (HBM) once per 8 steps — off the handoff path
        #pragma unroll
        for (int p = 0; p < 8; ++p) {
            int t = t0 + tc8 + p;
            outputs[((size_t)b_e * T + t) * H + hj] = oreg[p];
        }
    }

    cbuf[b_e * H + hj] = creg;
}

// ---------------------------------------------------------------------------
// init h slot 0 in producer-major layout: slot0[j>>3][b][j&7] = h0[b][j]
__global__ __launch_bounds__(256) void init_state(
    const float* __restrict__ h0, const float* __restrict__ c0,
    unsigned short* __restrict__ hb, float* __restrict__ cb)
{
    int i = blockIdx.x * 256 + threadIdx.x;    // 0..65535
    int b = i >> 10, j = i & 1023;
    hb[(size_t)(j >> 3) * 512 + b * 8 + (j & 7)] = f2bf(h0[i]);
    cb[i] = c0[i];
}

__global__ __launch_bounds__(128) void reset_flags(int* __restrict__ flags)
{
    __hip_atomic_store(&flags[threadIdx.x * FSTR], 0,
                       __ATOMIC_RELAXED, __HIP_MEMORY_SCOPE_AGENT);
}

// copy slot TC -> slot 0 (layout-identical dword copy)
__global__ __launch_bounds__(256) void copy_h(
    const unsigned short* __restrict__ src, unsigned short* __restrict__ dst)
{
    int i = blockIdx.x * 256 + threadIdx.x;    // dword index
    ((unsigned*)dst)[i] = ((const unsigned*)src)[i];
}

__global__ __launch_bounds__(256) void finalize(
    const float* __restrict__ outputs, const float* __restrict__ cfin,
    float* __restrict__ outh, float* __restrict__ outc)
{
    int i = blockIdx.x * 256 + threadIdx.x;    // 0..65535
    int b = i >> 10, j = i & 1023;
    outh[i] = outputs[((size_t)b * T + (T - 1)) * H + j];
    outc[i] = cfin[i];
}

// ---------------------------------------------------------------------------
extern "C" void kernel_launch(void* const* d_in, const int* in_sizes, int n_in,
                              void* d_out, int out_size, void* d_ws, size_t ws_size,
                              hipStream_t stream)
{
    const int*   tgt = (const int*)  d_in[0];
    const float* h0  = (const float*)d_in[1];
    const float* c0  = (const float*)d_in[2];
    const float* emb = (const float*)d_in[5];
    const float* Wih = (const float*)d_in[6];
    const float* Whh = (const float*)d_in[7];
    const float* bih = (const float*)d_in[8];
    const float* bhh = (const float*)d_in[9];

    float* out     = (float*)d_out;
    float* outputs = out;                                  // [B][T][H]
    float* out_h   = out + (size_t)B * T * H;
    float* out_c   = out_h + B * H;

    // ws layout — ~56.5 MB
    unsigned short* xproj  = (unsigned short*)d_ws;            // TC*B*G4
    unsigned short* xch    = xproj  + (size_t)TC * B * G4;     // TC*B*H
    unsigned short* wih    = xch    + (size_t)TC * B * H;      // G4*H
    unsigned short* whh    = wih    + (size_t)G4 * H;          // G4*H
    unsigned short* hchain = whh    + (size_t)G4 * H;          // (TC+1)*B*H
    float*          cbuf   = (float*)(hchain + (size_t)(TC + 1) * B * H);
    int*            flags  = (int*)(cbuf + (size_t)B * H);     // NBLK*FSTR

    cast_f32_bf16<<<2048, 256, 0, stream>>>(Wih, wih, (G4 * H) / 8);
    cast_f32_bf16<<<2048, 256, 0, stream>>>(Whh, whh, (G4 * H) / 8);
    init_state<<<(B * H) / 256, 256, 0, stream>>>(h0, c0, hchain, cbuf);
    reset_flags<<<1, NBLK, 0, stream>>>(flags);

    for (int ci = 0; ci < NCH; ++ci) {
        gather_x<<<(TC * B) / 2, 256, 0, stream>>>(tgt, emb, xch, ci * TC);
        gemm_xproj<<<(TC * B / 128) * (G4 / 128), 256, 0, stream>>>(xch, wih, xproj);
        if (ci) copy_h<<<(B * H / 2) / 256, 256, 0, stream>>>(
                    hchain + (size_t)TC * B * H, hchain);
        int t0 = ci * TC;
        void* args[] = { (void*)&xproj, (void*)&whh, (void*)&bih, (void*)&bhh,
                         (void*)&hchain, (void*)&cbuf, (void*)&outputs,
                         (void*)&flags, (void*)&t0 };
        hipLaunchCooperativeKernel((void*)lstm_chunk, dim3(NBLK), dim3(512),
                                   args, 0, stream);
    }
    finalize<<<(B * H) / 256, 256, 0, stream>>>(outputs, cbuf, out_h, out_c);
}